// Round 6
// baseline (816.191 us; speedup 1.0000x reference)
//
#include <hip/hip_runtime.h>
#include <stdint.h>

typedef __bf16 bf16x8 __attribute__((ext_vector_type(8)));
typedef float f32x4 __attribute__((ext_vector_type(4)));

__device__ __forceinline__ unsigned short f2bf(float f) {
    union { float f; uint32_t i; } v;
    v.f = f;
    uint32_t x = v.i;
    return (unsigned short)((x + 0x7FFFu + ((x >> 16) & 1u)) >> 16);  // RNE
}

// async global->LDS, 16B per lane. LDS dest is wave-uniform base + lane*16;
// the GLOBAL source address is per-lane free (this is what enables swizzling).
typedef __attribute__((address_space(3))) unsigned int lds_u32;
typedef __attribute__((address_space(1))) const unsigned int glob_u32;
__device__ __forceinline__ void gld16(const unsigned short* g, unsigned short* l) {
    __builtin_amdgcn_global_load_lds((glob_u32*)g, (lds_u32*)l, 16, 0, 0);
}

// ---------------------------------------------------------------------------
// All weight prep in ONE launch (range-dispatch on blockIdx.x, 9220 blocks).
// ---------------------------------------------------------------------------
__global__ __launch_bounds__(256) void prep_weights(
    const float* __restrict__ Wq, const float* __restrict__ Wk,
    const float* __restrict__ Wm, const float* __restrict__ W1,
    const float* __restrict__ W2, const float* __restrict__ bq,
    const float* __restrict__ bk,
    unsigned short* __restrict__ wqb, unsigned short* __restrict__ wkb,
    unsigned short* __restrict__ wmb, unsigned short* __restrict__ w1b,
    unsigned short* __restrict__ w2b, float* __restrict__ bqp,
    float* __restrict__ bkp)
{
    const int b = blockIdx.x, t = threadIdx.x;
    if (b < 2048) {
        const float* in = (b < 1024) ? Wq : Wk;
        unsigned short* out = (b < 1024) ? wqb : wkb;
        const int i = ((b & 1023) * 256 + t) * 4;
        const int row = i >> 10, col = i & 1023;
        const float4 v = *(const float4*)(in + ((row & 63) * 16 + (row >> 6)) * 1024 + col);
        out[i + 0] = f2bf(v.x); out[i + 1] = f2bf(v.y);
        out[i + 2] = f2bf(v.z); out[i + 3] = f2bf(v.w);
    } else if (b < 3072) {
        const int i = ((b - 2048) * 256 + t) * 4;
        const int row = i >> 10, c0 = i & 1023;
        const float* r = Wm + (size_t)row * 1024;
#pragma unroll
        for (int j = 0; j < 4; ++j) {
            const int c = c0 + j;
            wmb[i + j] = f2bf(r[(c & 63) * 16 + (c >> 6)]);
        }
    } else if (b < 7168) {
        const int i = ((b - 3072) * 256 + t) * 4;
        const float4 v = *(const float4*)(W1 + i);
        w1b[i + 0] = f2bf(v.x); w1b[i + 1] = f2bf(v.y);
        w1b[i + 2] = f2bf(v.z); w1b[i + 3] = f2bf(v.w);
    } else if (b < 9216) {
        const int i = ((b - 7168) * 256 + t) * 4;
        const float4 v = *(const float4*)(W2 + i);
        w2b[i + 0] = f2bf(v.x); w2b[i + 1] = f2bf(v.y);
        w2b[i + 2] = f2bf(v.z); w2b[i + 3] = f2bf(v.w);
    } else {
        const int o = (b - 9216) * 256 + t;
        const int src = (o & 63) * 16 + (o >> 6);
        bqp[o] = bq[src];
        bkp[o] = bk[src];
    }
}

// ---------------------------------------------------------------------------
// f32 [R][C] -> bf16 [C][R], batched over blockIdx.z (proj).
// ---------------------------------------------------------------------------
__global__ __launch_bounds__(256) void cvt_transpose(
    const float* __restrict__ in, unsigned short* __restrict__ out,
    int R, int C)
{
    __shared__ unsigned short tile[32][33];
    const size_t bo = (size_t)blockIdx.z * R * C;
    const int c0 = blockIdx.x * 32, r0 = blockIdx.y * 32;
    const int tx = threadIdx.x & 31, ty = threadIdx.x >> 5;
#pragma unroll
    for (int i = 0; i < 4; ++i)
        tile[ty + i * 8][tx] = f2bf(in[bo + (size_t)(r0 + ty + i * 8) * C + (c0 + tx)]);
    __syncthreads();
#pragma unroll
    for (int i = 0; i < 4; ++i)
        out[bo + (size_t)(c0 + ty + i * 8) * R + (r0 + tx)] = tile[tx][ty + i * 8];
}

// Fused x + source transpose: z = tensor*4 + batch.
__global__ __launch_bounds__(256) void cvt_transpose_xs(
    const float* __restrict__ x, const float* __restrict__ s,
    unsigned short* __restrict__ xt, unsigned short* __restrict__ st)
{
    __shared__ unsigned short tile[32][33];
    const int z = blockIdx.z;
    const float* in = (z < 4) ? x : s;
    unsigned short* out = (z < 4) ? xt : st;
    const size_t bo = (size_t)(z & 3) * 1024 * 4096;
    const int c0 = blockIdx.x * 32, r0 = blockIdx.y * 32;
    const int tx = threadIdx.x & 31, ty = threadIdx.x >> 5;
#pragma unroll
    for (int i = 0; i < 4; ++i)
        tile[ty + i * 8][tx] = f2bf(in[bo + (size_t)(r0 + ty + i * 8) * 4096 + (c0 + tx)]);
    __syncthreads();
#pragma unroll
    for (int i = 0; i < 4; ++i)
        out[bo + (size_t)(c0 + ty + i * 8) * 1024 + (r0 + tx)] = tile[tx][ty + i * 8];
}

// ---------------------------------------------------------------------------
// OLD 128x128 2-barrier GEMM. Kept ONLY for the kp projection (N'=128 < 256).
// ---------------------------------------------------------------------------
template<int LDA, int LDB, int LDC, int KD, int SPLIT, bool CONCAT>
__global__ __launch_bounds__(256) void gemm_bt(
    const unsigned short* __restrict__ A,
    const unsigned short* __restrict__ A2, int K1,
    const unsigned short* __restrict__ BT,
    unsigned short* __restrict__ C, float* __restrict__ Cf,
    long long strideA, long long strideB, long long strideC,
    const float* __restrict__ bias_m,
    const float* __restrict__ bias_n,
    const float* __restrict__ bn_g,
    const float* __restrict__ bn_b,
    const float* __restrict__ bn_mu,
    const float* __restrict__ bn_var)
{
    constexpr int KPB = KD / SPLIT;
    __shared__ __align__(16) unsigned short As[128 * 64];
    __shared__ __align__(16) unsigned short Bs[128 * 64];

    const int z = blockIdx.z;
    const int batch = z / SPLIT;
    const int kbase = (z % SPLIT) * KPB;
    const int m0 = blockIdx.y * 128, n0 = blockIdx.x * 128;
    const unsigned short* Ab  = A + (size_t)batch * strideA;
    const unsigned short* A2b = CONCAT ? A2 + (size_t)batch * strideA
                                       : (const unsigned short*)0;
    const unsigned short* Bb = BT + (size_t)batch * strideB;

    const int t = threadIdx.x;
    const int lane = t & 63, wid = t >> 6;
    const int wm = wid >> 1, wn = wid & 1;
    const int r16 = lane & 15, quad = lane >> 4;

    f32x4 acc[4][4];
    const f32x4 zf = {0.f, 0.f, 0.f, 0.f};
#pragma unroll
    for (int i = 0; i < 4; ++i)
#pragma unroll
        for (int j = 0; j < 4; ++j) acc[i][j] = zf;

    for (int kt = kbase; kt < kbase + KPB; kt += 64) {
        const unsigned short* Asrc = Ab;
        int kk = kt;
        if (CONCAT && kt >= K1) { Asrc = A2b; kk = kt - K1; }
#pragma unroll
        for (int i = 0; i < 4; ++i) {
            const int p = i * 256 + t;
            const int row = p >> 3, slot = p & 7;
            const int kc = (slot ^ (row & 7)) * 8;
            gld16(&Asrc[(size_t)(m0 + row) * LDA + kk + kc], &As[p * 8]);
            gld16(&Bb[(size_t)(n0 + row) * LDB + kt + kc], &Bs[p * 8]);
        }
        __syncthreads();
#pragma unroll
        for (int s = 0; s < 2; ++s) {
            bf16x8 af[4], bfb[4];
#pragma unroll
            for (int i = 0; i < 4; ++i) {
                const int ra = wm * 64 + i * 16 + r16;
                const int rb = wn * 64 + i * 16 + r16;
                af[i]  = *(const bf16x8*)&As[(ra * 8 + ((s * 4 + quad) ^ (ra & 7))) * 8];
                bfb[i] = *(const bf16x8*)&Bs[(rb * 8 + ((s * 4 + quad) ^ (rb & 7))) * 8];
            }
#pragma unroll
            for (int mi = 0; mi < 4; ++mi)
#pragma unroll
                for (int ni = 0; ni < 4; ++ni)
                    acc[mi][ni] = __builtin_amdgcn_mfma_f32_16x16x32_bf16(
                        af[mi], bfb[ni], acc[mi][ni], 0, 0, 0);
        }
        __syncthreads();
    }

    unsigned short* Cb = C ? C + (size_t)z * strideC : (unsigned short*)0;
    float* Cfb = Cf ? Cf + (size_t)z * strideC : (float*)0;
    const bool has_bn = (bn_g != 0);
#pragma unroll
    for (int ni = 0; ni < 4; ++ni) {
        const int gn = n0 + wn * 64 + ni * 16 + r16;
        const float addn = bias_n ? bias_n[gn] : 0.f;
        float g = 1.f, bb = 0.f, mu = 0.f, rstd = 1.f;
        if (has_bn) {
            g = bn_g[gn]; bb = bn_b[gn]; mu = bn_mu[gn];
            rstd = rsqrtf(bn_var[gn] + 1e-3f);
        }
#pragma unroll
        for (int mi = 0; mi < 4; ++mi) {
            const int gm0 = m0 + wm * 64 + mi * 16 + quad * 4;
#pragma unroll
            for (int r = 0; r < 4; ++r) {
                float v = acc[mi][ni][r] + addn;
                if (bias_m) v += bias_m[gm0 + r];
                if (has_bn) { v = g * (v - mu) * rstd + bb; v = fmaxf(v, 0.f); }
                const size_t idx = (size_t)(gm0 + r) * LDC + gn;
                if (Cfb) Cfb[idx] = v;
                else     Cb[idx]  = f2bf(v);
            }
        }
    }
}

// ---------------------------------------------------------------------------
// 256x256 GEMM v6: ONE __syncthreads per K-tile, reads-first issue order.
//
// r0-r5 post-mortem: five schedule variants all ~152 us, MfmaUtil ~38%.
// Cycle model: MFMA 2484 cyc/K-tile/CU, LDS traffic 256KB ~= 2300-3000 cyc
// -> observed 5890 = the two pipes running SERIALLY. Mechanism: barrier-
// delimited read phases with in-flight DMA force compiler-inserted vmcnt
// before every read cluster + phase lockstep resonance (all waves read
// together, then all MFMA together).
//
// v6 body per K-tile X: {24 ds_reads of X -> stage X+1 into other buffer
// (8 gld16) -> sched_barrier -> 64 MFMA -> __syncthreads}. Properties:
//  - at read-issue time ZERO DMA outstanding (drained at previous sync)
//    -> compiler's conservative vmcnt-before-reads is a free no-op;
//  - reads + MFMAs in one unbroken region -> compiler's counted lgkmcnt
//    lets the LDS pipe serve late reads DURING early MFMAs;
//  - __syncthreads' vmcnt(0)+lgkmcnt(0) drain waits on DMA issued ~3000
//    cyc earlier (>> 900 cyc HBM latency) -> free; and it IS the publish
//    + write-safety proof (no manual waitcnt anywhere -> race-free).
// ---------------------------------------------------------------------------
#define PRIO1 __builtin_amdgcn_s_setprio(1)
#define PRIO0 __builtin_amdgcn_s_setprio(0)

#define ST_A(dst, kt, i0, i1) do {                                          \
    const unsigned short* S_ = Ab; long long kk_ = (kt);                    \
    if (CONCAT && (kt) >= K1) { S_ = A2b; kk_ = (kt) - K1; }                \
    gld16(&S_[offA[i0] + kk_], (dst) + po[i0]);                             \
    gld16(&S_[offA[i1] + kk_], (dst) + po[i1]); } while (0)

#define ST_B(dst, kt, i0, i1) do {                                          \
    gld16(&Bb[offB[i0] + (kt)], (dst) + po[i0]);                            \
    gld16(&Bb[offB[i1] + (kt)], (dst) + po[i1]); } while (0)

// Fragment reads for one ks-half (ks in {0,1}): 8 A-frags + 4 B-frags.
// Row r of acc corresponds to tile row wm*128 + r*16 (r = mh*4+mi).
#define RD_A_KS(ks, AC, av) do {                                            \
    _Pragma("unroll") for (int i = 0; i < 8; ++i) {                         \
        const int ra = wm * 128 + i * 16 + r16;                             \
        av[i] = *(const bf16x8*)&(AC)[(ra * 8 + (((ks) * 4 + quad) ^ (ra & 7))) * 8]; \
    } } while (0)

#define RD_B_KS(ks, BC, bv) do {                                            \
    _Pragma("unroll") for (int j = 0; j < 4; ++j) {                         \
        const int rb = wn * 64 + j * 16 + r16;                              \
        bv[j] = *(const bf16x8*)&(BC)[(rb * 8 + (((ks) * 4 + quad) ^ (rb & 7))) * 8]; \
    } } while (0)

#define MFMA_KS(av, bv) do {                                                \
    _Pragma("unroll") for (int i = 0; i < 8; ++i)                           \
    _Pragma("unroll") for (int j = 0; j < 4; ++j)                           \
        acc[i][j] = __builtin_amdgcn_mfma_f32_16x16x32_bf16(                \
            av[i], bv[j], acc[i][j], 0, 0, 0); } while (0)

#define TILE_BODY(XV, AC, BC, AN, BN_) do {                                 \
    /* all 24 reads of tile XV (b first: first MFMA deps earliest) */       \
    RD_B_KS(0, BC, b0); RD_A_KS(0, AC, a0);                                 \
    RD_B_KS(1, BC, b1); RD_A_KS(1, AC, a1);                                 \
    /* stage tile XV+1 into the other buffer; drained by the sync below */  \
    if ((XV) + 1 < nt) {                                                    \
        const int kt1_ = ((XV) + 1) * 64;                                   \
        ST_A(AN, kt1_, 0, 2); ST_A(AN, kt1_, 1, 3);                         \
        ST_B(BN_, kt1_, 0, 1); ST_B(BN_, kt1_, 2, 3);                       \
    }                                                                       \
    __builtin_amdgcn_sched_barrier(0);  /* pin load issue above MFMAs */    \
    PRIO1; MFMA_KS(a0, b0); MFMA_KS(a1, b1); PRIO0;                         \
    __syncthreads();                                                        \
} while (0)

template<int LDA, int LDB, int LDC, int KD, int GX, int RN, int RM, bool CONCAT>
__global__ __launch_bounds__(512, 2) void gemm256(
    const unsigned short* __restrict__ A,
    const unsigned short* __restrict__ A2, int K1,
    const unsigned short* __restrict__ BT,
    unsigned short* __restrict__ C, float* __restrict__ Cf,
    long long strideA, long long strideB, long long strideC,
    const float* __restrict__ bias_m,
    const float* __restrict__ bias_n,
    const float* __restrict__ bn_g,
    const float* __restrict__ bn_b,
    const float* __restrict__ bn_mu,
    const float* __restrict__ bn_var)
{
    static_assert(KD % 128 == 0, "nt must be even");
    constexpr int nt = KD / 64;
    constexpr int TILE = 256 * 64;
    __shared__ __align__(16) unsigned short As0[TILE];
    __shared__ __align__(16) unsigned short As1[TILE];
    __shared__ __align__(16) unsigned short Bs0[TILE];
    __shared__ __align__(16) unsigned short Bs1[TILE];

    const int batch = blockIdx.z;
    // Per-XCD rectangle RN x RM (kept from r5; neutral but not harmful).
    constexpr int CX = GX / RN;
    const int f = blockIdx.y * GX + blockIdx.x;
    const int xcd = f & 7, local = f >> 3;
    const int xc = xcd % CX, xr = xcd / CX;
    const int n0 = (xc * RN + (local % RN)) * 256;
    const int m0 = (xr * RM + (local / RN)) * 256;

    const unsigned short* Ab  = A + (size_t)batch * strideA;
    const unsigned short* A2b = CONCAT ? A2 + (size_t)batch * strideA
                                       : (const unsigned short*)0;
    const unsigned short* Bb  = BT + (size_t)batch * strideB;

    const int t = threadIdx.x;
    const int lane = t & 63, wid = t >> 6;
    const int wm = wid >> 2, wn = wid & 3;       // 2 x 4 wave grid
    const int r16 = lane & 15, quad = lane >> 4;

    // Precomputed staging offsets (statically indexed only).
    long long offA[4], offB[4];
    int po[4];
#pragma unroll
    for (int i = 0; i < 4; ++i) {
        const int p = i * 512 + t, row = p >> 3;
        const int kc = ((p & 7) ^ (row & 7)) * 8;
        po[i] = p * 8;
        offA[i] = (long long)(m0 + row) * LDA + kc;
        offB[i] = (long long)(n0 + row) * LDB + kc;
    }

    f32x4 acc[8][4];
    const f32x4 zf = {0.f, 0.f, 0.f, 0.f};
#pragma unroll
    for (int i = 0; i < 8; ++i)
#pragma unroll
        for (int j = 0; j < 4; ++j) acc[i][j] = zf;

    bf16x8 a0[8], a1[8], b0[4], b1[4];

    // Prologue: stage T0 into buf0; __syncthreads drains (vmcnt 0) and
    // publishes it across all waves.
    ST_A(As0, 0, 0, 2); ST_A(As0, 0, 1, 3);
    ST_B(Bs0, 0, 0, 1); ST_B(Bs0, 0, 2, 3);
    __syncthreads();

#pragma unroll 1
    for (int X2 = 0; X2 < nt; X2 += 2) {
        TILE_BODY(X2,     As0, Bs0, As1, Bs1);
        TILE_BODY(X2 + 1, As1, Bs1, As0, Bs0);
    }

    unsigned short* Cb = C ? C + (size_t)batch * strideC : (unsigned short*)0;
    float* Cfb = Cf ? Cf + (size_t)batch * strideC : (float*)0;
    const bool has_bn = (bn_g != 0);

    // Per-ni column params hoisted; ni innermost so both 32B halves of each
    // 64B line are written back-to-back (write-combining; bf16 C path).
    float addn4[4], g4[4], b4[4], mu4[4], rs4[4];
#pragma unroll
    for (int ni = 0; ni < 4; ++ni) {
        const int gn = n0 + wn * 64 + ni * 16 + r16;
        addn4[ni] = bias_n ? bias_n[gn] : 0.f;
        if (has_bn) {
            g4[ni] = bn_g[gn]; b4[ni] = bn_b[gn]; mu4[ni] = bn_mu[gn];
            rs4[ni] = rsqrtf(bn_var[gn] + 1e-3f);
        }
    }
#pragma unroll
    for (int mi = 0; mi < 8; ++mi) {
        const int gm0 = m0 + wm * 128 + mi * 16 + quad * 4;
#pragma unroll
        for (int r = 0; r < 4; ++r) {
            const float bm_ = bias_m ? bias_m[gm0 + r] : 0.f;
            const size_t rowb = (size_t)(gm0 + r) * LDC + n0 + wn * 64 + r16;
#pragma unroll
            for (int ni = 0; ni < 4; ++ni) {
                float v = acc[mi][ni][r] + addn4[ni] + bm_;
                if (has_bn) {
                    v = g4[ni] * (v - mu4[ni]) * rs4[ni] + b4[ni];
                    v = fmaxf(v, 0.f);
                }
                if (Cfb) Cfb[rowb + ni * 16] = v;
                else     Cb[rowb + ni * 16]  = f2bf(v);
            }
        }
    }
}

#undef TILE_BODY
#undef MFMA_KS
#undef RD_B_KS
#undef RD_A_KS
#undef ST_B
#undef ST_A
#undef PRIO0
#undef PRIO1

// kp split-K reduce: kpb[b][j] = bf16( sum_p acc[b*8+p][j] )
__global__ __launch_bounds__(256) void reduce_kp(
    const float* __restrict__ acc, unsigned short* __restrict__ kpb)
{
    const int j = (blockIdx.x * 256 + threadIdx.x) * 4;
    const int b = j >> 17, jj = j & 131071;
    const float* base = acc + (size_t)b * 8 * 131072 + jj;
    float4 s = *(const float4*)base;
#pragma unroll
    for (int p = 1; p < 8; ++p) {
        const float4 v = *(const float4*)(base + (size_t)p * 131072);
        s.x += v.x; s.y += v.y; s.z += v.z; s.w += v.w;
    }
    kpb[j + 0] = f2bf(s.x); kpb[j + 1] = f2bf(s.y);
    kpb[j + 2] = f2bf(s.z); kpb[j + 3] = f2bf(s.w);
}

// ---------------------------------------------------------------------------
// MFMA flash-attention (unchanged; channel order o' = h*64+dh).
// ---------------------------------------------------------------------------
__global__ __launch_bounds__(256) void attn_fused(
    const unsigned short* __restrict__ qT,
    const unsigned short* __restrict__ kp,
    unsigned short* __restrict__ msgT)
{
    constexpr int QS = 72, KS = 72, VS = 136, PS = 136;
    __shared__ __align__(16) unsigned short QKP[128 * QS + 128 * KS];
    __shared__ __align__(16) unsigned short Vs[64 * VS];
    unsigned short* Qs = QKP;
    unsigned short* Ks = QKP + 128 * QS;
    unsigned short* Ps = QKP;

    const int t = threadIdx.x;
    const int lane = t & 63, w = t >> 6;
    const int r16 = lane & 15, quad = lane >> 4;
    const int h = blockIdx.y, n0 = blockIdx.x * 128;
    const size_t b = blockIdx.z;

    const unsigned short* qbase = qT + (b * 4096 + n0) * 1024 + h * 64;
    const unsigned short* kbase = kp + (b * 1024 + h * 64) * 128;

#pragma unroll
    for (int i = 0; i < 4; ++i) {
        const int c = i * 256 + t;
        const int n = c >> 3, dh0 = (c & 7) * 8;
        *(int4*)&Qs[n * QS + dh0] = *(const int4*)&qbase[(size_t)n * 1024 + dh0];
    }
#pragma unroll
    for (int i = 0; i < 4; ++i) {
        const int c = i * 256 + t;
        const int kkq = c & 3, dh = (c >> 2) & 63, kkh = c >> 8;
        const int kk0 = kkh * 32 + kkq * 8;
        const bf16x8 v = *(const bf16x8*)&kbase[(size_t)dh * 128 + kk0];
        *(bf16x8*)&Vs[dh * VS + kk0] = v;
        const unsigned short* vs = (const unsigned short*)&v;
#pragma unroll
        for (int j = 0; j < 8; ++j) Ks[(kk0 + j) * KS + dh] = vs[j];
    }
    __syncthreads();

    f32x4 S[2][8];
    const f32x4 zf = {0.f, 0.f, 0.f, 0.f};
#pragma unroll
    for (int mi = 0; mi < 2; ++mi)
#pragma unroll
        for (int ni = 0; ni < 8; ++ni) S[mi][ni] = zf;

    bf16x8 aq[2][2];
#pragma unroll
    for (int mi = 0; mi < 2; ++mi)
#pragma unroll
        for (int ks = 0; ks < 2; ++ks)
            aq[mi][ks] = *(const bf16x8*)&Qs[(w * 32 + mi * 16 + r16) * QS + ks * 32 + quad * 8];
#pragma unroll
    for (int ni = 0; ni < 8; ++ni) {
        const bf16x8 b0 = *(const bf16x8*)&Ks[(ni * 16 + r16) * KS + quad * 8];
        const bf16x8 b1 = *(const bf16x8*)&Ks[(ni * 16 + r16) * KS + 32 + quad * 8];
#pragma unroll
        for (int mi = 0; mi < 2; ++mi) {
            S[mi][ni] = __builtin_amdgcn_mfma_f32_16x16x32_bf16(aq[mi][0], b0, S[mi][ni], 0, 0, 0);
            S[mi][ni] = __builtin_amdgcn_mfma_f32_16x16x32_bf16(aq[mi][1], b1, S[mi][ni], 0, 0, 0);
        }
    }

    __syncthreads();

    float linv[2][4];
#pragma unroll
    for (int mi = 0; mi < 2; ++mi) {
        float e[8][4];
        float rs0 = 0.f, rs1 = 0.f, rs2 = 0.f, rs3 = 0.f;
#pragma unroll
        for (int ni = 0; ni < 8; ++ni) {
            e[ni][0] = __expf(S[mi][ni][0] * 0.125f); rs0 += e[ni][0];
            e[ni][1] = __expf(S[mi][ni][1] * 0.125f); rs1 += e[ni][1];
            e[ni][2] = __expf(S[mi][ni][2] * 0.125f); rs2 += e[ni][2];
            e[ni][3] = __expf(S[mi][ni][3] * 0.125f); rs3 += e[ni][3];
        }
        float rs[4] = {rs0, rs1, rs2, rs3};
#pragma unroll
        for (int r = 0; r < 4; ++r) {
            float s = rs[r];
            s += __shfl_xor(s, 1); s += __shfl_xor(s, 2);
            s += __shfl_xor(s, 4); s += __shfl_xor(s, 8);
            linv[mi][r] = 1.f / s;
        }
#pragma unroll
        for (int ni = 0; ni < 8; ++ni)
#pragma unroll
            for (int r = 0; r < 4; ++r)
                Ps[(w * 32 + mi * 16 + quad * 4 + r) * PS + ni * 16 + r16] = f2bf(e[ni][r]);
    }
    __syncthreads();

    f32x4 O[2][4];
#pragma unroll
    for (int mi = 0; mi < 2; ++mi)
#pragma unroll
        for (int ni = 0; ni < 4; ++ni) O[mi][ni] = zf;

    bf16x8 ap[2][4];
#pragma unroll
    for (int mi = 0; mi < 2; ++mi)
#pragma unroll
        for (int ks = 0; ks < 4; ++ks)
            ap[mi][ks] = *(const bf16x8*)&Ps[(w * 32 + mi * 16 + r16) * PS + ks * 32 + quad * 8];
#pragma unroll
    for (int ni = 0; ni < 4; ++ni)
#pragma unroll
        for (int ks = 0; ks < 4; ++ks) {
            const bf16x8 bv = *(const bf16x8*)&Vs[(ni * 16 + r16) * VS + ks * 32 + quad * 8];
#pragma unroll
            for (int mi = 0; mi < 2; ++mi)
                O[mi][ni] = __builtin_amdgcn_mfma_f32_16x16x32_bf16(ap[mi][ks], bv, O[mi][ni], 0, 0, 0);
        }

    unsigned short* ob = msgT + (b * 4096 + n0) * 1024 + h * 64;
#pragma unroll
    for (int mi = 0; mi < 2; ++mi)
#pragma unroll
        for (int ni = 0; ni < 4; ++ni)
#pragma unroll
            for (int r = 0; r < 4; ++r)
                ob[(size_t)(w * 32 + mi * 16 + quad * 4 + r) * 1024 + ni * 16 + r16] =
                    f2bf(O[mi][ni][r] * linv[mi][r]);
}

// ---------------------------------------------------------------------------
extern "C" void kernel_launch(void* const* d_in, const int* in_sizes, int n_in,
                              void* d_out, int out_size, void* d_ws, size_t ws_size,
                              hipStream_t stream)
{
    (void)in_sizes; (void)n_in; (void)out_size; (void)ws_size;
    const float* x    = (const float*)d_in[0];
    const float* srcp = (const float*)d_in[1];
    const float* Wq   = (const float*)d_in[2];
    const float* bq   = (const float*)d_in[3];
    const float* Wk   = (const float*)d_in[4];
    const float* bk   = (const float*)d_in[5];
    const float* proj = (const float*)d_in[6];
    const float* Wm   = (const float*)d_in[7];
    const float* bm   = (const float*)d_in[8];
    const float* W1   = (const float*)d_in[9];
    const float* b1   = (const float*)d_in[10];
    const float* gam  = (const float*)d_in[11];
    const float* bet  = (const float*)d_in[12];
    const float* mu   = (const float*)d_in[13];
    const float* var  = (const float*)d_in[14];
    const float* W2   = (const float*)d_in[15];
    const float* b2   = (const float*)d_in[16];
    float* out = (float*)d_out;
    unsigned short* ws = (unsigned short*)d_ws;

    const long long E = 16777216LL;  // 4*4096*1024
    unsigned short* xt  = ws;
    unsigned short* st  = xt + E;
    unsigned short* qt  = st + E;
    unsigned short* kc  = qt + E;
    unsigned short* ht  = kc + E;
    unsigned short* pT  = ht + 2 * E;
    unsigned short* kpb = pT + 524288;
    unsigned short* wqb = kpb + 524288;
    unsigned short* wkb = wqb + 1048576;
    unsigned short* wmb = wkb + 1048576;
    unsigned short* w1b = wmb + 1048576;
    unsigned short* w2b = w1b + 4194304;
    float* bqp = (float*)(w2b + 2097152);
    float* bkp = bqp + 1024;
    float* kpacc = (float*)ht;  // kp split-K partials alias ht (not yet live)

    cvt_transpose_xs<<<dim3(128, 32, 8), 256, 0, stream>>>(x, srcp, xt, st);
    cvt_transpose<<<dim3(4, 128, 1), 256, 0, stream>>>(proj, pT, 4096, 128);
    prep_weights<<<9220, 256, 0, stream>>>(Wq, Wk, Wm, W1, W2, bq, bk,
                                           wqb, wkb, wmb, w1b, w2b, bqp, bkp);

    // q = Wq @ x   (gx=4, gy=16; A=xt big -> rect 4n x 2m)
    gemm256<1024, 1024, 1024, 1024, 4, 4, 2, false><<<dim3(4, 16, 4), 512, 0, stream>>>(
        xt, nullptr, 1024, wqb, qt, nullptr,
        4096LL * 1024, 0LL, 4096LL * 1024, nullptr, bqp,
        nullptr, nullptr, nullptr, nullptr);
    // kc = Wk @ source  (gx=16, gy=4; B=st big -> rect 2n x 4m)
    gemm256<1024, 1024, 4096, 1024, 16, 2, 4, false><<<dim3(16, 4, 4), 512, 0, stream>>>(
        wkb, nullptr, 1024, st, kc, nullptr,
        0LL, 4096LL * 1024, 1024LL * 4096, bkp, nullptr,
        nullptr, nullptr, nullptr, nullptr);
    // kp projection: N'=128 too narrow for the 256-tile — keep 128-tile split-K.
    gemm_bt<4096, 4096, 128, 4096, 8, false><<<dim3(1, 8, 32), 256, 0, stream>>>(
        kc, nullptr, 4096, pT, nullptr, kpacc,
        1024LL * 4096, 0LL, 1024LL * 128, nullptr, nullptr,
        nullptr, nullptr, nullptr, nullptr);
    reduce_kp<<<512, 256, 0, stream>>>(kpacc, kpb);
    attn_fused<<<dim3(32, 16, 4), 256, 0, stream>>>(qt, kpb, qt);
    // merge  (gx=4, gy=16; A=qt big -> rect 4n x 2m)
    gemm256<1024, 1024, 1024, 1024, 4, 4, 2, false><<<dim3(4, 16, 4), 512, 0, stream>>>(
        qt, nullptr, 1024, wmb, st, nullptr,
        4096LL * 1024, 0LL, 4096LL * 1024, nullptr, bm,
        nullptr, nullptr, nullptr, nullptr);
    // mlp1 + BN + ReLU  (gx=8, gy=16; A=xt/st big -> rect 8n x 2m)
    gemm256<1024, 2048, 2048, 2048, 8, 8, 2, true><<<dim3(8, 16, 4), 512, 0, stream>>>(
        xt, st, 1024, w1b, ht, nullptr,
        4096LL * 1024, 0LL, 4096LL * 2048, nullptr, b1,
        gam, bet, mu, var);
    // mlp2 -> f32 out  (gx=16, gy=4; B=ht big -> rect 2n x 4m)
    gemm256<2048, 2048, 4096, 2048, 16, 2, 4, false><<<dim3(16, 4, 4), 512, 0, stream>>>(
        w2b, nullptr, 2048, ht, nullptr, out,
        0LL, 4096LL * 2048, 1024LL * 4096, b2, nullptr,
        nullptr, nullptr, nullptr, nullptr);
}

// Round 7
// 593.718 us; speedup vs baseline: 1.3747x; 1.3747x over previous
//
#include <hip/hip_runtime.h>
#include <stdint.h>

typedef __bf16 bf16x8 __attribute__((ext_vector_type(8)));
typedef float f32x4 __attribute__((ext_vector_type(4)));

__device__ __forceinline__ unsigned short f2bf(float f) {
    union { float f; uint32_t i; } v;
    v.f = f;
    uint32_t x = v.i;
    return (unsigned short)((x + 0x7FFFu + ((x >> 16) & 1u)) >> 16);  // RNE
}

// async global->LDS, 16B per lane. LDS dest is wave-uniform base + lane*16;
// the GLOBAL source address is per-lane free (this is what enables swizzling).
typedef __attribute__((address_space(3))) unsigned int lds_u32;
typedef __attribute__((address_space(1))) const unsigned int glob_u32;
__device__ __forceinline__ void gld16(const unsigned short* g, unsigned short* l) {
    __builtin_amdgcn_global_load_lds((glob_u32*)g, (lds_u32*)l, 16, 0, 0);
}

// ---------------------------------------------------------------------------
// All weight prep in ONE launch (range-dispatch on blockIdx.x, 9220 blocks).
// ---------------------------------------------------------------------------
__global__ __launch_bounds__(256) void prep_weights(
    const float* __restrict__ Wq, const float* __restrict__ Wk,
    const float* __restrict__ Wm, const float* __restrict__ W1,
    const float* __restrict__ W2, const float* __restrict__ bq,
    const float* __restrict__ bk,
    unsigned short* __restrict__ wqb, unsigned short* __restrict__ wkb,
    unsigned short* __restrict__ wmb, unsigned short* __restrict__ w1b,
    unsigned short* __restrict__ w2b, float* __restrict__ bqp,
    float* __restrict__ bkp)
{
    const int b = blockIdx.x, t = threadIdx.x;
    if (b < 2048) {
        const float* in = (b < 1024) ? Wq : Wk;
        unsigned short* out = (b < 1024) ? wqb : wkb;
        const int i = ((b & 1023) * 256 + t) * 4;
        const int row = i >> 10, col = i & 1023;
        const float4 v = *(const float4*)(in + ((row & 63) * 16 + (row >> 6)) * 1024 + col);
        out[i + 0] = f2bf(v.x); out[i + 1] = f2bf(v.y);
        out[i + 2] = f2bf(v.z); out[i + 3] = f2bf(v.w);
    } else if (b < 3072) {
        const int i = ((b - 2048) * 256 + t) * 4;
        const int row = i >> 10, c0 = i & 1023;
        const float* r = Wm + (size_t)row * 1024;
#pragma unroll
        for (int j = 0; j < 4; ++j) {
            const int c = c0 + j;
            wmb[i + j] = f2bf(r[(c & 63) * 16 + (c >> 6)]);
        }
    } else if (b < 7168) {
        const int i = ((b - 3072) * 256 + t) * 4;
        const float4 v = *(const float4*)(W1 + i);
        w1b[i + 0] = f2bf(v.x); w1b[i + 1] = f2bf(v.y);
        w1b[i + 2] = f2bf(v.z); w1b[i + 3] = f2bf(v.w);
    } else if (b < 9216) {
        const int i = ((b - 7168) * 256 + t) * 4;
        const float4 v = *(const float4*)(W2 + i);
        w2b[i + 0] = f2bf(v.x); w2b[i + 1] = f2bf(v.y);
        w2b[i + 2] = f2bf(v.z); w2b[i + 3] = f2bf(v.w);
    } else {
        const int o = (b - 9216) * 256 + t;
        const int src = (o & 63) * 16 + (o >> 6);
        bqp[o] = bq[src];
        bkp[o] = bk[src];
    }
}

// ---------------------------------------------------------------------------
// f32 [R][C] -> bf16 [C][R], batched over blockIdx.z (proj).
// ---------------------------------------------------------------------------
__global__ __launch_bounds__(256) void cvt_transpose(
    const float* __restrict__ in, unsigned short* __restrict__ out,
    int R, int C)
{
    __shared__ unsigned short tile[32][33];
    const size_t bo = (size_t)blockIdx.z * R * C;
    const int c0 = blockIdx.x * 32, r0 = blockIdx.y * 32;
    const int tx = threadIdx.x & 31, ty = threadIdx.x >> 5;
#pragma unroll
    for (int i = 0; i < 4; ++i)
        tile[ty + i * 8][tx] = f2bf(in[bo + (size_t)(r0 + ty + i * 8) * C + (c0 + tx)]);
    __syncthreads();
#pragma unroll
    for (int i = 0; i < 4; ++i)
        out[bo + (size_t)(c0 + ty + i * 8) * R + (r0 + tx)] = tile[tx][ty + i * 8];
}

// z<4: x -> xt (bf16 transpose [N,D]).  z>=4: source -> sb (bf16 straight
// copy [D,N]; the reassociated kp path needs source row-major, no transpose).
__global__ __launch_bounds__(256) void cvt_transpose_xs(
    const float* __restrict__ x, const float* __restrict__ s,
    unsigned short* __restrict__ xt, unsigned short* __restrict__ sb)
{
    __shared__ unsigned short tile[32][33];
    const int z = blockIdx.z;
    const size_t bo = (size_t)(z & 3) * 1024 * 4096;
    const int c0 = blockIdx.x * 32, r0 = blockIdx.y * 32;
    const int tx = threadIdx.x & 31, ty = threadIdx.x >> 5;
    if (z >= 4) {
#pragma unroll
        for (int i = 0; i < 4; ++i) {
            const size_t idx = bo + (size_t)(r0 + ty + i * 8) * 4096 + (c0 + tx);
            sb[idx] = f2bf(s[idx]);
        }
        return;
    }
#pragma unroll
    for (int i = 0; i < 4; ++i)
        tile[ty + i * 8][tx] = f2bf(x[bo + (size_t)(r0 + ty + i * 8) * 4096 + (c0 + tx)]);
    __syncthreads();
#pragma unroll
    for (int i = 0; i < 4; ++i)
        xt[bo + (size_t)(c0 + ty + i * 8) * 1024 + (r0 + tx)] = tile[tx][ty + i * 8];
}

// cs[k'] = sum_n proj[n][k'], computed from pT (bf16 [128][4096]). 1 block/k'.
__global__ __launch_bounds__(256) void colsum_pT(
    const unsigned short* __restrict__ pT, float* __restrict__ cs)
{
    __shared__ float red[4];
    const int k = blockIdx.x, t = threadIdx.x;
    const unsigned short* row = pT + (size_t)k * 4096;
    float s = 0.f;
#pragma unroll
    for (int it = 0; it < 2; ++it) {
        const int4 v = *(const int4*)&row[(t + it * 256) * 8];
        const unsigned short* u = (const unsigned short*)&v;
#pragma unroll
        for (int j = 0; j < 8; ++j) {
            union { uint32_t i; float f; } w; w.i = (uint32_t)u[j] << 16;
            s += w.f;
        }
    }
#pragma unroll
    for (int o = 1; o < 64; o <<= 1) s += __shfl_xor(s, o);
    if ((t & 63) == 0) red[t >> 6] = s;
    __syncthreads();
    if (t == 0) cs[k] = red[0] + red[1] + red[2] + red[3];
}

// ---------------------------------------------------------------------------
// 128x128 2-barrier GEMM (split-K capable). Used for the two small GEMMs of
// the reassociated kp path (N' or M = 128 — too narrow for the 256 tile).
// ---------------------------------------------------------------------------
template<int LDA, int LDB, int LDC, int KD, int SPLIT, bool CONCAT>
__global__ __launch_bounds__(256) void gemm_bt(
    const unsigned short* __restrict__ A,
    const unsigned short* __restrict__ A2, int K1,
    const unsigned short* __restrict__ BT,
    unsigned short* __restrict__ C, float* __restrict__ Cf,
    long long strideA, long long strideB, long long strideC,
    const float* __restrict__ bias_m,
    const float* __restrict__ bias_n,
    const float* __restrict__ bn_g,
    const float* __restrict__ bn_b,
    const float* __restrict__ bn_mu,
    const float* __restrict__ bn_var)
{
    constexpr int KPB = KD / SPLIT;
    __shared__ __align__(16) unsigned short As[128 * 64];
    __shared__ __align__(16) unsigned short Bs[128 * 64];

    const int z = blockIdx.z;
    const int batch = z / SPLIT;
    const int kbase = (z % SPLIT) * KPB;
    const int m0 = blockIdx.y * 128, n0 = blockIdx.x * 128;
    const unsigned short* Ab  = A + (size_t)batch * strideA;
    const unsigned short* A2b = CONCAT ? A2 + (size_t)batch * strideA
                                       : (const unsigned short*)0;
    const unsigned short* Bb = BT + (size_t)batch * strideB;

    const int t = threadIdx.x;
    const int lane = t & 63, wid = t >> 6;
    const int wm = wid >> 1, wn = wid & 1;
    const int r16 = lane & 15, quad = lane >> 4;

    f32x4 acc[4][4];
    const f32x4 zf = {0.f, 0.f, 0.f, 0.f};
#pragma unroll
    for (int i = 0; i < 4; ++i)
#pragma unroll
        for (int j = 0; j < 4; ++j) acc[i][j] = zf;

    for (int kt = kbase; kt < kbase + KPB; kt += 64) {
        const unsigned short* Asrc = Ab;
        int kk = kt;
        if (CONCAT && kt >= K1) { Asrc = A2b; kk = kt - K1; }
#pragma unroll
        for (int i = 0; i < 4; ++i) {
            const int p = i * 256 + t;
            const int row = p >> 3, slot = p & 7;
            const int kc = (slot ^ (row & 7)) * 8;
            gld16(&Asrc[(size_t)(m0 + row) * LDA + kk + kc], &As[p * 8]);
            gld16(&Bb[(size_t)(n0 + row) * LDB + kt + kc], &Bs[p * 8]);
        }
        __syncthreads();
#pragma unroll
        for (int s = 0; s < 2; ++s) {
            bf16x8 af[4], bfb[4];
#pragma unroll
            for (int i = 0; i < 4; ++i) {
                const int ra = wm * 64 + i * 16 + r16;
                const int rb = wn * 64 + i * 16 + r16;
                af[i]  = *(const bf16x8*)&As[(ra * 8 + ((s * 4 + quad) ^ (ra & 7))) * 8];
                bfb[i] = *(const bf16x8*)&Bs[(rb * 8 + ((s * 4 + quad) ^ (rb & 7))) * 8];
            }
#pragma unroll
            for (int mi = 0; mi < 4; ++mi)
#pragma unroll
                for (int ni = 0; ni < 4; ++ni)
                    acc[mi][ni] = __builtin_amdgcn_mfma_f32_16x16x32_bf16(
                        af[mi], bfb[ni], acc[mi][ni], 0, 0, 0);
        }
        __syncthreads();
    }

    unsigned short* Cb = C ? C + (size_t)z * strideC : (unsigned short*)0;
    float* Cfb = Cf ? Cf + (size_t)z * strideC : (float*)0;
    const bool has_bn = (bn_g != 0);
#pragma unroll
    for (int ni = 0; ni < 4; ++ni) {
        const int gn = n0 + wn * 64 + ni * 16 + r16;
        const float addn = bias_n ? bias_n[gn] : 0.f;
        float g = 1.f, bb = 0.f, mu = 0.f, rstd = 1.f;
        if (has_bn) {
            g = bn_g[gn]; bb = bn_b[gn]; mu = bn_mu[gn];
            rstd = rsqrtf(bn_var[gn] + 1e-3f);
        }
#pragma unroll
        for (int mi = 0; mi < 4; ++mi) {
            const int gm0 = m0 + wm * 64 + mi * 16 + quad * 4;
#pragma unroll
            for (int r = 0; r < 4; ++r) {
                float v = acc[mi][ni][r] + addn;
                if (bias_m) v += bias_m[gm0 + r];
                if (has_bn) { v = g * (v - mu) * rstd + bb; v = fmaxf(v, 0.f); }
                const size_t idx = (size_t)(gm0 + r) * LDC + gn;
                if (Cfb) Cfb[idx] = v;
                else     Cb[idx]  = f2bf(v);
            }
        }
    }
}

// ---------------------------------------------------------------------------
// 256x256 GEMM, TWO-phase K-step (8 waves 2Mx4N, BK=64, dbuf LDS 128 KiB).
// Round-3 proven form (best measured: 151-152 us on the MLP shapes).
// ---------------------------------------------------------------------------
#define BAR   __builtin_amdgcn_s_barrier()
#define LGKM0 asm volatile("s_waitcnt lgkmcnt(0)" ::: "memory")
#define PRIO1 __builtin_amdgcn_s_setprio(1)
#define PRIO0 __builtin_amdgcn_s_setprio(0)

#define ST_A(dst, kt, i0, i1) do {                                          \
    const unsigned short* S_ = Ab; long long kk_ = (kt);                    \
    if (CONCAT && (kt) >= K1) { S_ = A2b; kk_ = (kt) - K1; }                \
    gld16(&S_[offA[i0] + kk_], (dst) + po[i0]);                             \
    gld16(&S_[offA[i1] + kk_], (dst) + po[i1]); } while (0)

#define ST_B(dst, kt, i0, i1) do {                                          \
    gld16(&Bb[offB[i0] + (kt)], (dst) + po[i0]);                            \
    gld16(&Bb[offB[i1] + (kt)], (dst) + po[i1]); } while (0)

#define RD_A(mh, AC) do {                                                   \
    _Pragma("unroll") for (int mi = 0; mi < 4; ++mi) {                      \
        const int ra = wm * 128 + (mh) * 64 + mi * 16 + r16;                \
        _Pragma("unroll") for (int ks = 0; ks < 2; ++ks) {                  \
            const int c_ = ks * 4 + quad;                                   \
            a[mi][ks] = *(const bf16x8*)&(AC)[(ra * 8 + (c_ ^ (ra & 7))) * 8]; \
        } } } while (0)

#define RD_B(np, BC) do {                                                   \
    _Pragma("unroll") for (int i = 0; i < 2; ++i) {                         \
        const int rb = wn * 64 + ((np) * 2 + i) * 16 + r16;                 \
        _Pragma("unroll") for (int ks = 0; ks < 2; ++ks) {                  \
            const int c_ = ks * 4 + quad;                                   \
            b[(np) * 2 + i][ks] = *(const bf16x8*)&(BC)[(rb * 8 + (c_ ^ (rb & 7))) * 8]; \
        } } } while (0)

#define MFMA_PH(mh, np) do {                                                \
    _Pragma("unroll") for (int mi = 0; mi < 4; ++mi)                        \
    _Pragma("unroll") for (int i = 0; i < 2; ++i)                           \
    _Pragma("unroll") for (int ks = 0; ks < 2; ++ks)                        \
        acc[(mh) * 4 + mi][(np) * 2 + i] =                                  \
            __builtin_amdgcn_mfma_f32_16x16x32_bf16(                        \
                a[mi][ks], b[(np) * 2 + i][ks],                             \
                acc[(mh) * 4 + mi][(np) * 2 + i], 0, 0, 0); } while (0)

#define TILE_BODY(XV, AC, BC, AN, BN_) do {                                 \
    const int kt1_ = ((XV) + 1) * 64;                                       \
    const bool g1_ = ((XV) + 1) < nt;                                       \
    /* phase A: A(mh0)+all-B reads; stage U0,U1,U2(X+1) -> next buf */      \
    RD_A(0, AC); RD_B(0, BC); RD_B(1, BC);                                  \
    if (g1_) { ST_A(AN, kt1_, 0, 2); ST_B(BN_, kt1_, 0, 1);                 \
               ST_B(BN_, kt1_, 2, 3);                                       \
               asm volatile("s_waitcnt vmcnt(6)" ::: "memory"); }           \
    else     { asm volatile("s_waitcnt vmcnt(0)" ::: "memory"); }           \
    BAR; LGKM0; PRIO1; MFMA_PH(0, 0); MFMA_PH(0, 1); PRIO0; BAR;            \
    /* phase B: A(mh1) reads; stage U3(X+1) -> next buf */                  \
    RD_A(1, AC);                                                            \
    if (g1_) { ST_A(AN, kt1_, 1, 3);                                        \
               asm volatile("s_waitcnt vmcnt(2)" ::: "memory"); }           \
    else     { asm volatile("s_waitcnt vmcnt(0)" ::: "memory"); }           \
    BAR; LGKM0; PRIO1; MFMA_PH(1, 1); MFMA_PH(1, 0); PRIO0; BAR;            \
} while (0)

template<int LDA, int LDB, int LDC, int KD, bool CONCAT>
__global__ __launch_bounds__(512, 2) void gemm256(
    const unsigned short* __restrict__ A,
    const unsigned short* __restrict__ A2, int K1,
    const unsigned short* __restrict__ BT,
    unsigned short* __restrict__ C, float* __restrict__ Cf,
    long long strideA, long long strideB, long long strideC,
    const float* __restrict__ bias_m,
    const float* __restrict__ bias_n,
    const float* __restrict__ bn_g,
    const float* __restrict__ bn_b,
    const float* __restrict__ bn_mu,
    const float* __restrict__ bn_var)
{
    static_assert(KD % 128 == 0, "nt must be even");
    constexpr int nt = KD / 64;
    constexpr int TILE = 256 * 64;
    __shared__ __align__(16) unsigned short As0[TILE];
    __shared__ __align__(16) unsigned short As1[TILE];
    __shared__ __align__(16) unsigned short Bs0[TILE];
    __shared__ __align__(16) unsigned short Bs1[TILE];

    const int batch = blockIdx.z;
    // Bijective XCD-contiguous tile remap (all grids here have nwg % 8 == 0).
    const int gx = gridDim.x;
    const int nwg = gx * gridDim.y;
    int flat = blockIdx.y * gx + blockIdx.x;
    flat = (flat & 7) * (nwg >> 3) + (flat >> 3);
    const int n0 = (flat % gx) * 256;
    const int m0 = (flat / gx) * 256;

    const unsigned short* Ab  = A + (size_t)batch * strideA;
    const unsigned short* A2b = CONCAT ? A2 + (size_t)batch * strideA
                                       : (const unsigned short*)0;
    const unsigned short* Bb  = BT + (size_t)batch * strideB;

    const int t = threadIdx.x;
    const int lane = t & 63, wid = t >> 6;
    const int wm = wid >> 2, wn = wid & 3;       // 2 x 4 wave grid
    const int r16 = lane & 15, quad = lane >> 4;

    // Precomputed staging offsets (statically indexed only).
    long long offA[4], offB[4];
    int po[4];
#pragma unroll
    for (int i = 0; i < 4; ++i) {
        const int p = i * 512 + t, row = p >> 3;
        const int kc = ((p & 7) ^ (row & 7)) * 8;
        po[i] = p * 8;
        offA[i] = (long long)(m0 + row) * LDA + kc;
        offB[i] = (long long)(n0 + row) * LDB + kc;
    }

    f32x4 acc[8][4];
    const f32x4 zf = {0.f, 0.f, 0.f, 0.f};
#pragma unroll
    for (int i = 0; i < 8; ++i)
#pragma unroll
        for (int j = 0; j < 4; ++j) acc[i][j] = zf;

    bf16x8 a[4][2], b[4][2];

    // Prologue: all 4 units of T0 (queue order U0,U1,U2,U3); vmcnt(2)
    // completes U0,U1,U2 (covers phase A's reads); U3 stays in flight and
    // is completed by phase A's vmcnt(6) before phase B reads it.
    ST_A(As0, 0, 0, 2);
    ST_B(Bs0, 0, 0, 1);
    ST_B(Bs0, 0, 2, 3);
    ST_A(As0, 0, 1, 3);
    asm volatile("s_waitcnt vmcnt(2)" ::: "memory");
    BAR;

#pragma unroll 1
    for (int X2 = 0; X2 < nt; X2 += 2) {
        TILE_BODY(X2,     As0, Bs0, As1, Bs1);
        TILE_BODY(X2 + 1, As1, Bs1, As0, Bs0);
    }

    unsigned short* Cb = C ? C + (size_t)batch * strideC : (unsigned short*)0;
    float* Cfb = Cf ? Cf + (size_t)batch * strideC : (float*)0;
    const bool has_bn = (bn_g != 0);

    // Per-ni column params hoisted; ni innermost so both 32B halves of each
    // 64B line are written back-to-back (write-combining; bf16 C path).
    float addn4[4], g4[4], b4[4], mu4[4], rs4[4];
#pragma unroll
    for (int ni = 0; ni < 4; ++ni) {
        const int gn = n0 + wn * 64 + ni * 16 + r16;
        addn4[ni] = bias_n ? bias_n[gn] : 0.f;
        if (has_bn) {
            g4[ni] = bn_g[gn]; b4[ni] = bn_b[gn]; mu4[ni] = bn_mu[gn];
            rs4[ni] = rsqrtf(bn_var[gn] + 1e-3f);
        }
    }
#pragma unroll
    for (int mi = 0; mi < 8; ++mi) {
        const int gm0 = m0 + wm * 128 + mi * 16 + quad * 4;
#pragma unroll
        for (int r = 0; r < 4; ++r) {
            const float bm_ = bias_m ? bias_m[gm0 + r] : 0.f;
            const size_t rowb = (size_t)(gm0 + r) * LDC + n0 + wn * 64 + r16;
#pragma unroll
            for (int ni = 0; ni < 4; ++ni) {
                float v = acc[mi][ni][r] + addn4[ni] + bm_;
                if (has_bn) {
                    v = g4[ni] * (v - mu4[ni]) * rs4[ni] + b4[ni];
                    v = fmaxf(v, 0.f);
                }
                if (Cfb) Cfb[rowb + ni * 16] = v;
                else     Cb[rowb + ni * 16]  = f2bf(v);
            }
        }
    }
}

#undef TILE_BODY
#undef MFMA_PH
#undef RD_B
#undef RD_A
#undef ST_B
#undef ST_A
#undef PRIO0
#undef PRIO1
#undef LGKM0
#undef BAR

// split-K reduce: out[b][j] = bf16( sum_p acc[b*8+p][j] )
__global__ __launch_bounds__(256) void reduce_kp(
    const float* __restrict__ acc, unsigned short* __restrict__ kpb)
{
    const int j = (blockIdx.x * 256 + threadIdx.x) * 4;
    const int b = j >> 17, jj = j & 131071;
    const float* base = acc + (size_t)b * 8 * 131072 + jj;
    float4 s = *(const float4*)base;
#pragma unroll
    for (int p = 1; p < 8; ++p) {
        const float4 v = *(const float4*)(base + (size_t)p * 131072);
        s.x += v.x; s.y += v.y; s.z += v.z; s.w += v.w;
    }
    kpb[j + 0] = f2bf(s.x); kpb[j + 1] = f2bf(s.y);
    kpb[j + 2] = f2bf(s.z); kpb[j + 3] = f2bf(s.w);
}

// split-K reduce + rank-1 bias: out[b][o'][k'] = sum_p acc + bk[o']*cs[k'].
// (kp = Wk@(src@proj) + bk*colsum(proj)^T — the reassociated Linformer path.)
__global__ __launch_bounds__(256) void reduce_kp2(
    const float* __restrict__ acc, const float* __restrict__ bkp,
    const float* __restrict__ cs, unsigned short* __restrict__ out)
{
    const int j = (blockIdx.x * 256 + threadIdx.x) * 4;
    const int b = j >> 17, jj = j & 131071;
    const int o = jj >> 7, kq = jj & 127;
    const float* base = acc + (size_t)b * 8 * 131072 + jj;
    float4 s = *(const float4*)base;
#pragma unroll
    for (int p = 1; p < 8; ++p) {
        const float4 v = *(const float4*)(base + (size_t)p * 131072);
        s.x += v.x; s.y += v.y; s.z += v.z; s.w += v.w;
    }
    const float bm = bkp[o];
    out[j + 0] = f2bf(s.x + bm * cs[kq + 0]);
    out[j + 1] = f2bf(s.y + bm * cs[kq + 1]);
    out[j + 2] = f2bf(s.z + bm * cs[kq + 2]);
    out[j + 3] = f2bf(s.w + bm * cs[kq + 3]);
}

// ---------------------------------------------------------------------------
// MFMA flash-attention (unchanged; channel order o' = h*64+dh).
// ---------------------------------------------------------------------------
__global__ __launch_bounds__(256) void attn_fused(
    const unsigned short* __restrict__ qT,
    const unsigned short* __restrict__ kp,
    unsigned short* __restrict__ msgT)
{
    constexpr int QS = 72, KS = 72, VS = 136, PS = 136;
    __shared__ __align__(16) unsigned short QKP[128 * QS + 128 * KS];
    __shared__ __align__(16) unsigned short Vs[64 * VS];
    unsigned short* Qs = QKP;
    unsigned short* Ks = QKP + 128 * QS;
    unsigned short* Ps = QKP;

    const int t = threadIdx.x;
    const int lane = t & 63, w = t >> 6;
    const int r16 = lane & 15, quad = lane >> 4;
    const int h = blockIdx.y, n0 = blockIdx.x * 128;
    const size_t b = blockIdx.z;

    const unsigned short* qbase = qT + (b * 4096 + n0) * 1024 + h * 64;
    const unsigned short* kbase = kp + (b * 1024 + h * 64) * 128;

#pragma unroll
    for (int i = 0; i < 4; ++i) {
        const int c = i * 256 + t;
        const int n = c >> 3, dh0 = (c & 7) * 8;
        *(int4*)&Qs[n * QS + dh0] = *(const int4*)&qbase[(size_t)n * 1024 + dh0];
    }
#pragma unroll
    for (int i = 0; i < 4; ++i) {
        const int c = i * 256 + t;
        const int kkq = c & 3, dh = (c >> 2) & 63, kkh = c >> 8;
        const int kk0 = kkh * 32 + kkq * 8;
        const bf16x8 v = *(const bf16x8*)&kbase[(size_t)dh * 128 + kk0];
        *(bf16x8*)&Vs[dh * VS + kk0] = v;
        const unsigned short* vs = (const unsigned short*)&v;
#pragma unroll
        for (int j = 0; j < 8; ++j) Ks[(kk0 + j) * KS + dh] = vs[j];
    }
    __syncthreads();

    f32x4 S[2][8];
    const f32x4 zf = {0.f, 0.f, 0.f, 0.f};
#pragma unroll
    for (int mi = 0; mi < 2; ++mi)
#pragma unroll
        for (int ni = 0; ni < 8; ++ni) S[mi][ni] = zf;

    bf16x8 aq[2][2];
#pragma unroll
    for (int mi = 0; mi < 2; ++mi)
#pragma unroll
        for (int ks = 0; ks < 2; ++ks)
            aq[mi][ks] = *(const bf16x8*)&Qs[(w * 32 + mi * 16 + r16) * QS + ks * 32 + quad * 8];
#pragma unroll
    for (int ni = 0; ni < 8; ++ni) {
        const bf16x8 b0 = *(const bf16x8*)&Ks[(ni * 16 + r16) * KS + quad * 8];
        const bf16x8 b1 = *(const bf16x8*)&Ks[(ni * 16 + r16) * KS + 32 + quad * 8];
#pragma unroll
        for (int mi = 0; mi < 2; ++mi) {
            S[mi][ni] = __builtin_amdgcn_mfma_f32_16x16x32_bf16(aq[mi][0], b0, S[mi][ni], 0, 0, 0);
            S[mi][ni] = __builtin_amdgcn_mfma_f32_16x16x32_bf16(aq[mi][1], b1, S[mi][ni], 0, 0, 0);
        }
    }

    __syncthreads();

    float linv[2][4];
#pragma unroll
    for (int mi = 0; mi < 2; ++mi) {
        float e[8][4];
        float rs0 = 0.f, rs1 = 0.f, rs2 = 0.f, rs3 = 0.f;
#pragma unroll
        for (int ni = 0; ni < 8; ++ni) {
            e[ni][0] = __expf(S[mi][ni][0] * 0.125f); rs0 += e[ni][0];
            e[ni][1] = __expf(S[mi][ni][1] * 0.125f); rs1 += e[ni][1];
            e[ni][2] = __expf(S[mi][ni][2] * 0.125f); rs2 += e[ni][2];
            e[ni][3] = __expf(S[mi][ni][3] * 0.125f); rs3 += e[ni][3];
        }
        float rs[4] = {rs0, rs1, rs2, rs3};
#pragma unroll
        for (int r = 0; r < 4; ++r) {
            float s = rs[r];
            s += __shfl_xor(s, 1); s += __shfl_xor(s, 2);
            s += __shfl_xor(s, 4); s += __shfl_xor(s, 8);
            linv[mi][r] = 1.f / s;
        }
#pragma unroll
        for (int ni = 0; ni < 8; ++ni)
#pragma unroll
            for (int r = 0; r < 4; ++r)
                Ps[(w * 32 + mi * 16 + quad * 4 + r) * PS + ni * 16 + r16] = f2bf(e[ni][r]);
    }
    __syncthreads();

    f32x4 O[2][4];
#pragma unroll
    for (int mi = 0; mi < 2; ++mi)
#pragma unroll
        for (int ni = 0; ni < 4; ++ni) O[mi][ni] = zf;

    bf16x8 ap[2][4];
#pragma unroll
    for (int mi = 0; mi < 2; ++mi)
#pragma unroll
        for (int ks = 0; ks < 4; ++ks)
            ap[mi][ks] = *(const bf16x8*)&Ps[(w * 32 + mi * 16 + r16) * PS + ks * 32 + quad * 8];
#pragma unroll
    for (int ni = 0; ni < 4; ++ni)
#pragma unroll
        for (int ks = 0; ks < 4; ++ks) {
            const bf16x8 bv = *(const bf16x8*)&Vs[(ni * 16 + r16) * VS + ks * 32 + quad * 8];
#pragma unroll
            for (int mi = 0; mi < 2; ++mi)
                O[mi][ni] = __builtin_amdgcn_mfma_f32_16x16x32_bf16(ap[mi][ks], bv, O[mi][ni], 0, 0, 0);
        }

    unsigned short* ob = msgT + (b * 4096 + n0) * 1024 + h * 64;
#pragma unroll
    for (int mi = 0; mi < 2; ++mi)
#pragma unroll
        for (int ni = 0; ni < 4; ++ni)
#pragma unroll
            for (int r = 0; r < 4; ++r)
                ob[(size_t)(w * 32 + mi * 16 + quad * 4 + r) * 1024 + ni * 16 + r16] =
                    f2bf(O[mi][ni][r] * linv[mi][r]);
}

// ---------------------------------------------------------------------------
extern "C" void kernel_launch(void* const* d_in, const int* in_sizes, int n_in,
                              void* d_out, int out_size, void* d_ws, size_t ws_size,
                              hipStream_t stream)
{
    (void)in_sizes; (void)n_in; (void)out_size; (void)ws_size;
    const float* x    = (const float*)d_in[0];
    const float* srcp = (const float*)d_in[1];
    const float* Wq   = (const float*)d_in[2];
    const float* bq   = (const float*)d_in[3];
    const float* Wk   = (const float*)d_in[4];
    const float* bk   = (const float*)d_in[5];
    const float* proj = (const float*)d_in[6];
    const float* Wm   = (const float*)d_in[7];
    const float* bm   = (const float*)d_in[8];
    const float* W1   = (const float*)d_in[9];
    const float* b1   = (const float*)d_in[10];
    const float* gam  = (const float*)d_in[11];
    const float* bet  = (const float*)d_in[12];
    const float* mu   = (const float*)d_in[13];
    const float* var  = (const float*)d_in[14];
    const float* W2   = (const float*)d_in[15];
    const float* b2   = (const float*)d_in[16];
    float* out = (float*)d_out;
    unsigned short* ws = (unsigned short*)d_ws;

    const long long E = 16777216LL;  // 4*4096*1024
    unsigned short* xt  = ws;            // x transposed [B,N,D] bf16
    unsigned short* sb  = xt + E;        // source bf16 [B,D,N]; later reused as merge output msgT
    unsigned short* qt  = sb + E;
    unsigned short* ks  = qt + E;        // freed kc slot: kp2 partials + cs + kp final
    unsigned short* ht  = ks + E;        // 2E
    unsigned short* pT  = ht + 2 * E;    // proj^T bf16 [128][4096]
    unsigned short* spb = pT + 524288;   // spT bf16 [B][128][1024]
    unsigned short* wqb = spb + 524288;
    unsigned short* wkb = wqb + 1048576;
    unsigned short* wmb = wkb + 1048576;
    unsigned short* w1b = wmb + 1048576;
    unsigned short* w2b = w1b + 4194304;
    float* bqp = (float*)(w2b + 2097152);
    float* bkp = bqp + 1024;
    float* kpacc  = (float*)ht;          // sp split-K partials alias ht (not yet live)
    float* kpacc2 = (float*)ks;          // kp2 split-K partials (32 x 131072 f32)
    float* cs     = kpacc2 + 32 * 131072;
    unsigned short* kpf = (unsigned short*)(cs + 128);  // kp bf16 [B][1024][128]

    cvt_transpose_xs<<<dim3(128, 32, 8), 256, 0, stream>>>(x, srcp, xt, sb);
    cvt_transpose<<<dim3(4, 128, 1), 256, 0, stream>>>(proj, pT, 4096, 128);
    prep_weights<<<9220, 256, 0, stream>>>(Wq, Wk, Wm, W1, W2, bq, bk,
                                           wqb, wkb, wmb, w1b, w2b, bqp, bkp);
    colsum_pT<<<128, 256, 0, stream>>>(pT, cs);

    // q = Wq @ x           (M=4096 seq, N'=1024 out-ch, K=1024)
    gemm256<1024, 1024, 1024, 1024, false><<<dim3(4, 16, 4), 512, 0, stream>>>(
        xt, nullptr, 1024, wqb, qt, nullptr,
        4096LL * 1024, 0LL, 4096LL * 1024, nullptr, bqp,
        nullptr, nullptr, nullptr, nullptr);

    // spT = proj^T @ src^T  (M=128 k', N'=1024 d, K=4096 n; split-K 8)
    gemm_bt<4096, 4096, 1024, 4096, 8, false><<<dim3(8, 1, 32), 256, 0, stream>>>(
        pT, nullptr, 4096, sb, nullptr, kpacc,
        0LL, 1024LL * 4096, 131072LL, nullptr, nullptr,
        nullptr, nullptr, nullptr, nullptr);
    reduce_kp<<<512, 256, 0, stream>>>(kpacc, spb);

    // kp = Wk @ sp + bk*cs^T  (M=1024 o', N'=128 k', K=1024 i; split-K 8)
    gemm_bt<1024, 1024, 128, 1024, 8, false><<<dim3(1, 8, 32), 256, 0, stream>>>(
        wkb, nullptr, 1024, spb, nullptr, kpacc2,
        0LL, 131072LL, 131072LL, nullptr, nullptr,
        nullptr, nullptr, nullptr, nullptr);
    reduce_kp2<<<512, 256, 0, stream>>>(kpacc2, bkp, cs, kpf);

    attn_fused<<<dim3(32, 16, 4), 256, 0, stream>>>(qt, kpf, qt);

    // merge                (M=4096 seq, N'=1024, K=1024) -> sb slot (msgT)
    gemm256<1024, 1024, 1024, 1024, false><<<dim3(4, 16, 4), 512, 0, stream>>>(
        qt, nullptr, 1024, wmb, sb, nullptr,
        4096LL * 1024, 0LL, 4096LL * 1024, nullptr, bm,
        nullptr, nullptr, nullptr, nullptr);
    // mlp1 + BN + ReLU     (M=4096, N'=2048, K=2048 concat)
    gemm256<1024, 2048, 2048, 2048, true><<<dim3(8, 16, 4), 512, 0, stream>>>(
        xt, sb, 1024, w1b, ht, nullptr,
        4096LL * 1024, 0LL, 4096LL * 2048, nullptr, b1,
        gam, bet, mu, var);
    // mlp2 -> f32 out      (M=1024 out-ch, N'=4096 seq, K=2048)
    gemm256<2048, 2048, 4096, 2048, false><<<dim3(16, 4, 4), 512, 0, stream>>>(
        w2b, nullptr, 2048, ht, nullptr, out,
        0LL, 4096LL * 2048, 1024LL * 4096, b2, nullptr,
        nullptr, nullptr, nullptr, nullptr);
}